// Round 1
// baseline (562.470 us; speedup 1.0000x reference)
//
#include <hip/hip_runtime.h>

// Problem constants (from reference): T=16, B=32, L=128, D_IN=D_OUT=512
constexpr int T_STEPS = 16;
constexpr int BLTOT   = 4096;   // B*L
constexpr int KDIM    = 512;    // D_IN
constexpr int NDIM    = 512;    // D_OUT

// Tile config
constexpr int BK   = 16;
constexpr int BM   = 128;       // 16 t-slices x 8 (b,l) rows
constexpr int BN   = 128;
constexpr int LDSS = BM + 4;    // padded stride (floats); 132*4=528B, 16B aligned

// Fused GEMM (h = x*W^T + b) + multistep LIF epilogue.
// Row mapping within the M-tile: local row r in [0,128): t = r & 15, bl = bl0 + (r >> 4).
// Thread (tm = tid>>5 in [0,8), tn = tid&31 in [0,32)) owns rows tm*16 + t (ALL 16 t,
// same bl = bl0+tm) and cols n0 + tn*4 + {0..3} -> LIF recurrence is thread-local.
__global__ __launch_bounds__(256, 4)
void fused_gemm_lif(const float* __restrict__ x,
                    const float* __restrict__ W,
                    const float* __restrict__ bias,
                    float* __restrict__ out) {
  __shared__ float As[BK][LDSS];
  __shared__ float Bs[BK][LDSS];

  const int tid = threadIdx.x;
  const int mb  = blockIdx.x;        // 512 bl-tiles
  const int nb  = blockIdx.y;        // 4 n-tiles
  const int bl0 = mb * 8;
  const int n0  = nb * BN;

  const int tn = tid & 31;
  const int tm = tid >> 5;

  // Staging: 128 rows x 16 k = 2048 floats = 512 float4; 2 per thread.
  // float4 index f: r = f>>2 (tile row), k-quad = (f&3)*4
  const int r0  = tid >> 2;               // rows 0..63   (f = tid)
  const int r1  = r0 + 64;                // rows 64..127 (f = tid+256)
  const int kq  = (tid & 3) * 4;          // same k-quad for both

  // global M row for A-tile rows
  const long mA0 = (long)(r0 & 15) * BLTOT + bl0 + (r0 >> 4);
  const long mA1 = (long)(r1 & 15) * BLTOT + bl0 + (r1 >> 4);

  const float* pA0 = x + mA0 * KDIM + kq;
  const float* pA1 = x + mA1 * KDIM + kq;
  const float* pB0 = W + (long)(n0 + r0) * KDIM + kq;
  const float* pB1 = W + (long)(n0 + r1) * KDIM + kq;

  float acc[16][4];
#pragma unroll
  for (int i = 0; i < 16; ++i)
#pragma unroll
    for (int j = 0; j < 4; ++j) acc[i][j] = 0.0f;

  for (int k0 = 0; k0 < KDIM; k0 += BK) {
    // issue global loads early (overlap with prior tile's compute)
    const float4 a0 = *(const float4*)(pA0 + k0);
    const float4 a1 = *(const float4*)(pA1 + k0);
    const float4 b0 = *(const float4*)(pB0 + k0);
    const float4 b1 = *(const float4*)(pB1 + k0);

    __syncthreads();  // previous tile's compute done before overwrite
#pragma unroll
    for (int j = 0; j < 4; ++j) {
      As[kq + j][r0] = ((const float*)&a0)[j];
      As[kq + j][r1] = ((const float*)&a1)[j];
      Bs[kq + j][r0] = ((const float*)&b0)[j];
      Bs[kq + j][r1] = ((const float*)&b1)[j];
    }
    __syncthreads();

#pragma unroll
    for (int k = 0; k < BK; ++k) {
      const float4 b4 = *(const float4*)&Bs[k][tn * 4];
      float4 a4[4];
#pragma unroll
      for (int q = 0; q < 4; ++q)
        a4[q] = *(const float4*)&As[k][tm * 16 + q * 4];
#pragma unroll
      for (int i = 0; i < 16; ++i) {
        const float av = ((const float*)&a4[i >> 2])[i & 3];
#pragma unroll
        for (int j = 0; j < 4; ++j)
          acc[i][j] += av * ((const float*)&b4)[j];
      }
    }
  }

  // Epilogue: bias + multistep LIF (tau=2, v_th=1, hard reset to 0), all in regs.
  const float4 bb = *(const float4*)(bias + n0 + tn * 4);
  const int bl = bl0 + tm;
  float v[4] = {0.0f, 0.0f, 0.0f, 0.0f};

#pragma unroll
  for (int t = 0; t < T_STEPS; ++t) {
    float4 s4;
#pragma unroll
    for (int j = 0; j < 4; ++j) {
      const float h = acc[t][j] + ((const float*)&bb)[j];
      float vj = v[j];
      vj = vj + (h - vj) * 0.5f;           // v += (x - v)/tau, tau=2 (exact /2)
      const bool fire = (vj >= 1.0f);
      ((float*)&s4)[j] = fire ? 1.0f : 0.0f;
      v[j] = fire ? 0.0f : vj;             // hard reset
    }
    *(float4*)(out + ((size_t)t * BLTOT + bl) * NDIM + n0 + tn * 4) = s4;
  }
}

extern "C" void kernel_launch(void* const* d_in, const int* in_sizes, int n_in,
                              void* d_out, int out_size, void* d_ws, size_t ws_size,
                              hipStream_t stream) {
  const float* x = (const float*)d_in[0];   // [16,32,128,512]
  const float* W = (const float*)d_in[1];   // [512,512]
  const float* b = (const float*)d_in[2];   // [512]
  float* out = (float*)d_out;               // [16,32,128,512] spikes

  dim3 grid(BLTOT / 8, NDIM / BN);          // (512, 4)
  fused_gemm_lif<<<grid, 256, 0, stream>>>(x, W, b, out);
}

// Round 2
// 448.352 us; speedup vs baseline: 1.2545x; 1.2545x over previous
//
#include <hip/hip_runtime.h>

using f32x4 = __attribute__((ext_vector_type(4))) float;
using s16x8 = __attribute__((ext_vector_type(8))) short;

constexpr int T_STEPS = 16;
constexpr int BLTOT   = 4096;   // B*L
constexpr int KDIM    = 512;
constexpr int NDIM    = 512;

constexpr int BM = 128, BN = 128, BK = 32;
constexpr int ROWB  = 80;               // padded LDS row stride bytes (32 bf16 = 64B + 16B pad)
constexpr int COMP  = 128 * ROWB;       // 10240 B per component plane
constexpr int BBASE = 3 * COMP;         // B planes start (30720)
// LDS total: 6 planes = 61440 B

// Row permutation within the 128-row M tile:
//   t(r)  = ((r>>4)&3)*4 + (r&3)
//   bl(r) = (r>>6)*4 + ((r>>2)&3)
// With MFMA C-layout row=(lane>>4)*4+reg, a thread's 4 m-frags x 4 regs cover
// all 16 t of ONE bl  ->  LIF runs entirely in registers.

__device__ __forceinline__ void split3_write(char* lds, float4 v, int off) {
  // Truncation split of 4 f32 into 3 bf16 planes; pack pairs into uint2 (8B stores).
  unsigned u[4], u1[4], u2[4];
  float r1[4], r2[4];
#pragma unroll
  for (int e = 0; e < 4; ++e) {
    float ve = ((const float*)&v)[e];
    u[e]  = __float_as_uint(ve);
    r1[e] = ve - __uint_as_float(u[e] & 0xFFFF0000u);
    u1[e] = __float_as_uint(r1[e]);
    r2[e] = r1[e] - __uint_as_float(u1[e] & 0xFFFF0000u);
    u2[e] = __float_as_uint(r2[e]);
  }
  uint2 hp, mp, lp;
  hp.x = (u[0]  >> 16) | (u[1]  & 0xFFFF0000u);
  hp.y = (u[2]  >> 16) | (u[3]  & 0xFFFF0000u);
  mp.x = (u1[0] >> 16) | (u1[1] & 0xFFFF0000u);
  mp.y = (u1[2] >> 16) | (u1[3] & 0xFFFF0000u);
  lp.x = (u2[0] >> 16) | (u2[1] & 0xFFFF0000u);
  lp.y = (u2[2] >> 16) | (u2[3] & 0xFFFF0000u);
  *(uint2*)(lds + off)            = hp;
  *(uint2*)(lds + off + COMP)     = mp;
  *(uint2*)(lds + off + 2 * COMP) = lp;
}

__global__ __launch_bounds__(256, 2)
void fused_mfma_lif(const float* __restrict__ x, const float* __restrict__ W,
                    const float* __restrict__ bias, float* __restrict__ out) {
  __shared__ __align__(16) char lds[6 * COMP];

  const int tid  = threadIdx.x;
  const int lane = tid & 63;
  const int wv   = tid >> 6;          // wave 0..3
  const int wm   = wv >> 1;           // wave m index (0..1)
  const int wn   = wv & 1;            // wave n index (0..1)
  const int bl0  = blockIdx.x * 8;
  const int n0   = blockIdx.y * BN;

  // ---- staging assignment: 4 float4 for A + 4 for B per thread ----
  const float* aptr[4];
  const float* bptr[4];
  int aw[4], bw[4];
#pragma unroll
  for (int i = 0; i < 4; ++i) {
    int f  = i * 256 + tid;           // float4 index 0..1023
    int r  = f >> 3;                  // tile row 0..127
    int kq = (f & 7) * 4;             // k offset in f32
    int t  = ((r >> 4) & 3) * 4 + (r & 3);
    int bl = (r >> 6) * 4 + ((r >> 2) & 3);
    aptr[i] = x + (size_t)(t * BLTOT + bl0 + bl) * KDIM + kq;
    bptr[i] = W + (size_t)(n0 + r) * KDIM + kq;
    aw[i] = r * ROWB + kq * 2;
    bw[i] = BBASE + r * ROWB + kq * 2;
  }

  f32x4 acc[4][4];
#pragma unroll
  for (int a = 0; a < 4; ++a)
#pragma unroll
    for (int b = 0; b < 4; ++b) acc[a][b] = (f32x4)(0.0f);

  // frag read byte offsets (comp 0); add c*COMP per component
  const int arow = (wm * 64 + (lane & 15)) * ROWB + (lane >> 4) * 16;
  const int brow = BBASE + (wn * 64 + (lane & 15)) * ROWB + (lane >> 4) * 16;

  float4 ar[4], br[4];
#pragma unroll
  for (int i = 0; i < 4; ++i) {
    ar[i] = *(const float4*)(aptr[i]);
    br[i] = *(const float4*)(bptr[i]);
  }

  for (int it = 0; it < 16; ++it) {
    __syncthreads();                  // previous compute done; LDS reusable
#pragma unroll
    for (int i = 0; i < 4; ++i) {
      split3_write(lds, ar[i], aw[i]);
      split3_write(lds, br[i], bw[i]);
    }
    __syncthreads();

    if (it < 15) {                    // prefetch next k-slab into regs
      const int ko = (it + 1) * BK;
#pragma unroll
      for (int i = 0; i < 4; ++i) {
        ar[i] = *(const float4*)(aptr[i] + ko);
        br[i] = *(const float4*)(bptr[i] + ko);
      }
    }

    // B fragments: 4 n-frags x 3 comps (held), A per m-frag
    s16x8 bf[4][3];
#pragma unroll
    for (int nf = 0; nf < 4; ++nf)
#pragma unroll
      for (int c = 0; c < 3; ++c)
        bf[nf][c] = *(const s16x8*)(lds + brow + nf * 16 * ROWB + c * COMP);

#pragma unroll
    for (int mf = 0; mf < 4; ++mf) {
      s16x8 af[3];
#pragma unroll
      for (int c = 0; c < 3; ++c)
        af[c] = *(const s16x8*)(lds + arow + mf * 16 * ROWB + c * COMP);
#pragma unroll
      for (int nf = 0; nf < 4; ++nf) {
        f32x4 c0 = acc[mf][nf];
        // smallest-magnitude products first
        c0 = __builtin_amdgcn_mfma_f32_16x16x32_bf16(af[2], bf[nf][0], c0, 0, 0, 0); // lo*hi
        c0 = __builtin_amdgcn_mfma_f32_16x16x32_bf16(af[0], bf[nf][2], c0, 0, 0, 0); // hi*lo
        c0 = __builtin_amdgcn_mfma_f32_16x16x32_bf16(af[1], bf[nf][1], c0, 0, 0, 0); // mid*mid
        c0 = __builtin_amdgcn_mfma_f32_16x16x32_bf16(af[1], bf[nf][0], c0, 0, 0, 0); // mid*hi
        c0 = __builtin_amdgcn_mfma_f32_16x16x32_bf16(af[0], bf[nf][1], c0, 0, 0, 0); // hi*mid
        c0 = __builtin_amdgcn_mfma_f32_16x16x32_bf16(af[0], bf[nf][0], c0, 0, 0, 0); // hi*hi
        acc[mf][nf] = c0;
      }
    }
  }

  // ---- epilogue: bias + 16-step LIF fully in registers ----
  const int G   = lane >> 4;
  const int bl  = bl0 + wm * 4 + G;
  const int col = lane & 15;
#pragma unroll
  for (int nf = 0; nf < 4; ++nf) {
    const int n = n0 + wn * 64 + nf * 16 + col;
    const float bb = bias[n];
    float v = 0.0f;
#pragma unroll
    for (int t = 0; t < T_STEPS; ++t) {
      const float h = ((const float*)&acc[t >> 2][nf])[t & 3] + bb;
      float vn = v + (h - v) * 0.5f;         // v += (x - v)/tau, tau=2
      const bool s = (vn >= 1.0f);
      out[(size_t)(t * BLTOT + bl) * NDIM + n] = s ? 1.0f : 0.0f;
      v = s ? 0.0f : vn;
    }
  }
}

extern "C" void kernel_launch(void* const* d_in, const int* in_sizes, int n_in,
                              void* d_out, int out_size, void* d_ws, size_t ws_size,
                              hipStream_t stream) {
  const float* x = (const float*)d_in[0];
  const float* W = (const float*)d_in[1];
  const float* b = (const float*)d_in[2];
  float* out = (float*)d_out;

  dim3 grid(BLTOT / 8, NDIM / BN);    // (512, 4)
  fused_mfma_lif<<<grid, 256, 0, stream>>>(x, W, b, out);
}

// Round 5
// 415.124 us; speedup vs baseline: 1.3549x; 1.0800x over previous
//
#include <hip/hip_runtime.h>

using f32x4 = __attribute__((ext_vector_type(4))) float;
using s16x8 = __attribute__((ext_vector_type(8))) short;

constexpr int T_STEPS = 16;
constexpr int BLTOT   = 4096;   // B*L
constexpr int KDIM    = 512;
constexpr int NDIM    = 512;

// ---- frag-plane workspace layout -------------------------------------------
// 1 frag-block = 1024 B = 64 lanes x 16 B (8 bf16): lane = q + 16*g holds
// elems [row q][k = ks*32 + g*8 .. +7] of one 16-row tile, one split plane c.
// B' at ws+0:    ((nt*16 + ks)*3 + c)*1024,  nt in [0,32), ks in [0,16)
// A' at ws+ABASE:(((mb*8+mt)*16 + ks)*3 + c)*1024, mb in [0,512), mt in [0,8)
constexpr size_t B_BYTES = 32ull * 16 * 3 * 1024;      //   1,572,864
constexpr size_t A_BYTES = 512ull * 8 * 16 * 3 * 1024; // 201,326,592
constexpr size_t ABASE   = B_BYTES;
constexpr size_t WS_NEED = A_BYTES + B_BYTES;

// M-row permutation (verified in round 2): tile row of m-tile mt, in-tile row q:
//   t  = (mt&3)*4 + (q&3)
//   bl = mb*8 + (mt>>2)*4 + (q>>2)
// With MFMA C-layout (col=lane&15, row=(lane>>4)*4+reg), each lane's acc regs
// cover all 16 t of ONE bl -> LIF recurrence is thread-local.

__device__ __forceinline__ void split8(const float* e, uint4& hp, uint4& mp, uint4& lp) {
  unsigned h[8], m[8], l[8];
#pragma unroll
  for (int j = 0; j < 8; ++j) {
    const float f = e[j];
    const unsigned u = __float_as_uint(f);
    h[j] = u >> 16;
    const float r1 = f - __uint_as_float(u & 0xFFFF0000u);
    const unsigned u1 = __float_as_uint(r1);
    m[j] = u1 >> 16;
    const float r2 = r1 - __uint_as_float(u1 & 0xFFFF0000u);
    l[j] = __float_as_uint(r2) >> 16;
  }
  hp = make_uint4(h[0] | (h[1] << 16), h[2] | (h[3] << 16),
                  h[4] | (h[5] << 16), h[6] | (h[7] << 16));
  mp = make_uint4(m[0] | (m[1] << 16), m[2] | (m[3] << 16),
                  m[4] | (m[5] << 16), m[6] | (m[7] << 16));
  lp = make_uint4(l[0] | (l[1] << 16), l[2] | (l[3] << 16),
                  l[4] | (l[5] << 16), l[6] | (l[7] << 16));
}

// ---- pre-pass: split W into B' (frag order) --------------------------------
__global__ void split_w(const float* __restrict__ W, char* __restrict__ ws) {
  const int tid = threadIdx.x;
  const int wid = blockIdx.x * 4 + (tid >> 6);   // 0..511 = nt*16 + ks
  const int lane = tid & 63;
  const int nt = wid >> 4, ks = wid & 15;
  const int q = lane & 15, g = lane >> 4;
  const float* src = W + (size_t)(nt * 16 + q) * KDIM + ks * 32 + g * 8;
  float e[8];
  *(float4*)&e[0] = *(const float4*)src;
  *(float4*)&e[4] = *(const float4*)(src + 4);
  uint4 hp, mp, lp;
  split8(e, hp, mp, lp);
  char* dst = ws + (size_t)wid * 3072 + lane * 16;
  *(uint4*)(dst)        = hp;
  *(uint4*)(dst + 1024) = mp;
  *(uint4*)(dst + 2048) = lp;
}

// ---- pre-pass: split x into A' (frag order, M-permuted) --------------------
__global__ void split_x(const float* __restrict__ x, char* __restrict__ ws) {
  const int tid = threadIdx.x;
  const int wid = blockIdx.x * 4 + (tid >> 6);   // 0..65535 = (mb*8+mt)*16 + ks
  const int lane = tid & 63;
  const int ks = wid & 15, mtile = wid >> 4;
  const int mt = mtile & 7, mb = mtile >> 3;
  const int q = lane & 15, g = lane >> 4;
  const int t  = (mt & 3) * 4 + (q & 3);
  const int bl = mb * 8 + (mt >> 2) * 4 + (q >> 2);
  const float* src = x + (size_t)(t * BLTOT + bl) * KDIM + ks * 32 + g * 8;
  float e[8];
  *(float4*)&e[0] = *(const float4*)src;
  *(float4*)&e[4] = *(const float4*)(src + 4);
  uint4 hp, mp, lp;
  split8(e, hp, mp, lp);
  char* dst = ws + ABASE + (size_t)wid * 3072 + lane * 16;
  *(uint4*)(dst)        = hp;
  *(uint4*)(dst + 1024) = mp;
  *(uint4*)(dst + 2048) = lp;
}

// ---- main: frag-plane GEMM (pure global_load_lds + MFMA) + LIF epilogue ----
__global__ __launch_bounds__(256, 2)
void gemm_lif_frag(const char* __restrict__ wsB, const char* __restrict__ wsA,
                   const float* __restrict__ bias, float* __restrict__ out) {
  __shared__ __align__(16) char lds[48 * 1024];   // A: 24 KB (8mt x 3c), B: 24 KB

  const int tid  = threadIdx.x;
  const int lane = tid & 63;
  const int wv   = tid >> 6;
  const int wm   = wv >> 1, wn = wv & 1;

  // XCD-chunked swizzle: 2048 blocks, 8 XCDs; nb innermost for A' L2 reuse.
  const int w    = blockIdx.x;
  const int orig = (w & 7) * 256 + (w >> 3);
  const int nb   = orig & 3;
  const int mb   = orig >> 2;

  // staging: waves 0,1 stage A (mt 0..7), waves 2,3 stage B (ntl 0..7);
  // 12 frag-blocks (4 sub-tiles x 3 comps) per wave per slab.
  const bool isA = (wv < 2);
  const int blk0 = isA ? (mb * 8 + wv * 4) : (nb * 8 + (wv - 2) * 4);
  const char* gbase = (isA ? wsA : wsB) + (size_t)blk0 * 49152 + lane * 16;
  char* ldsdst = lds + wv * 12288;

  f32x4 acc[4][4];
#pragma unroll
  for (int a = 0; a < 4; ++a)
#pragma unroll
    for (int b = 0; b < 4; ++b) acc[a][b] = (f32x4)(0.0f);

  int koff = 0;
  for (int ksl = 0; ksl < 16; ++ksl) {
#pragma unroll
    for (int i = 0; i < 12; ++i) {
      const int co = ((i / 3) * 48 + (i % 3)) * 1024;   // sub-tile stride 48KB, comp 1KB
      __builtin_amdgcn_global_load_lds(
          (const __attribute__((address_space(1))) void*)(gbase + koff + co),
          (__attribute__((address_space(3))) void*)(ldsdst + i * 1024), 16, 0, 0);
    }
    koff += 3072;
    __syncthreads();   // drain vmcnt -> slab visible in LDS

    s16x8 bf[4][3];
#pragma unroll
    for (int nf = 0; nf < 4; ++nf)
#pragma unroll
      for (int c = 0; c < 3; ++c)
        bf[nf][c] = *(const s16x8*)(lds + 24576 + ((wn * 4 + nf) * 3 + c) * 1024 + lane * 16);

#pragma unroll
    for (int mf = 0; mf < 4; ++mf) {
      s16x8 af[3];
#pragma unroll
      for (int c = 0; c < 3; ++c)
        af[c] = *(const s16x8*)(lds + ((wm * 4 + mf) * 3 + c) * 1024 + lane * 16);
#pragma unroll
      for (int nf = 0; nf < 4; ++nf) {
        f32x4 c0 = acc[mf][nf];
        c0 = __builtin_amdgcn_mfma_f32_16x16x32_bf16(af[2], bf[nf][0], c0, 0, 0, 0); // lo*hi
        c0 = __builtin_amdgcn_mfma_f32_16x16x32_bf16(af[0], bf[nf][2], c0, 0, 0, 0); // hi*lo
        c0 = __builtin_amdgcn_mfma_f32_16x16x32_bf16(af[1], bf[nf][1], c0, 0, 0, 0); // mid*mid
        c0 = __builtin_amdgcn_mfma_f32_16x16x32_bf16(af[1], bf[nf][0], c0, 0, 0, 0); // mid*hi
        c0 = __builtin_amdgcn_mfma_f32_16x16x32_bf16(af[0], bf[nf][1], c0, 0, 0, 0); // hi*mid
        c0 = __builtin_amdgcn_mfma_f32_16x16x32_bf16(af[0], bf[nf][0], c0, 0, 0, 0); // hi*hi
        acc[mf][nf] = c0;
      }
    }
    __syncthreads();   // all reads done before next slab overwrites
  }

  // ---- epilogue: bias + 16-step LIF in registers (verified mapping) ----
  const int G   = lane >> 4;
  const int bl  = mb * 8 + wm * 4 + G;
  const int col = lane & 15;
  const int n0  = nb * 128;
#pragma unroll
  for (int nf = 0; nf < 4; ++nf) {
    const int n = n0 + wn * 64 + nf * 16 + col;
    const float bb = bias[n];
    float v = 0.0f;
#pragma unroll
    for (int t = 0; t < T_STEPS; ++t) {
      const float h = ((const float*)&acc[t >> 2][nf])[t & 3] + bb;
      const float vn = v + (h - v) * 0.5f;   // v += (x - v)/tau, tau=2
      const bool s = (vn >= 1.0f);
      out[(size_t)(t * BLTOT + bl) * NDIM + n] = s ? 1.0f : 0.0f;
      v = s ? 0.0f : vn;
    }
  }
}

// ---- fallback (verified round-2 kernel) if ws is too small -----------------
constexpr int FB_ROWB  = 80;
constexpr int FB_COMP  = 128 * FB_ROWB;
constexpr int FB_BBASE = 3 * FB_COMP;

__device__ __forceinline__ void split3_write(char* lds, float4 v, int off) {
  unsigned u[4], u1[4], u2[4];
#pragma unroll
  for (int e = 0; e < 4; ++e) {
    float ve = ((const float*)&v)[e];
    u[e]  = __float_as_uint(ve);
    float r1 = ve - __uint_as_float(u[e] & 0xFFFF0000u);
    u1[e] = __float_as_uint(r1);
    float r2 = r1 - __uint_as_float(u1[e] & 0xFFFF0000u);
    u2[e] = __float_as_uint(r2);
  }
  uint2 hp, mp, lp;
  hp.x = (u[0]  >> 16) | (u[1]  & 0xFFFF0000u);
  hp.y = (u[2]  >> 16) | (u[3]  & 0xFFFF0000u);
  mp.x = (u1[0] >> 16) | (u1[1] & 0xFFFF0000u);
  mp.y = (u1[2] >> 16) | (u1[3] & 0xFFFF0000u);
  lp.x = (u2[0] >> 16) | (u2[1] & 0xFFFF0000u);
  lp.y = (u2[2] >> 16) | (u2[3] & 0xFFFF0000u);
  *(uint2*)(lds + off)               = hp;
  *(uint2*)(lds + off + FB_COMP)     = mp;
  *(uint2*)(lds + off + 2 * FB_COMP) = lp;
}

__global__ __launch_bounds__(256, 2)
void fused_mfma_lif_fb(const float* __restrict__ x, const float* __restrict__ W,
                       const float* __restrict__ bias, float* __restrict__ out) {
  __shared__ __align__(16) char lds[6 * FB_COMP];
  const int tid = threadIdx.x;
  const int lane = tid & 63;
  const int wv = tid >> 6, wm = wv >> 1, wn = wv & 1;
  const int bl0 = blockIdx.x * 8, n0 = blockIdx.y * 128;

  const float* aptr[4]; const float* bptr[4];
  int aw[4], bw[4];
#pragma unroll
  for (int i = 0; i < 4; ++i) {
    int f = i * 256 + tid, r = f >> 3, kq = (f & 7) * 4;
    int t = ((r >> 4) & 3) * 4 + (r & 3);
    int bl = (r >> 6) * 4 + ((r >> 2) & 3);
    aptr[i] = x + (size_t)(t * BLTOT + bl0 + bl) * KDIM + kq;
    bptr[i] = W + (size_t)(n0 + r) * KDIM + kq;
    aw[i] = r * FB_ROWB + kq * 2;
    bw[i] = FB_BBASE + r * FB_ROWB + kq * 2;
  }
  f32x4 acc[4][4];
#pragma unroll
  for (int a = 0; a < 4; ++a)
#pragma unroll
    for (int b = 0; b < 4; ++b) acc[a][b] = (f32x4)(0.0f);

  const int arow = (wm * 64 + (lane & 15)) * FB_ROWB + (lane >> 4) * 16;
  const int brow = FB_BBASE + (wn * 64 + (lane & 15)) * FB_ROWB + (lane >> 4) * 16;

  float4 ar[4], br[4];
#pragma unroll
  for (int i = 0; i < 4; ++i) { ar[i] = *(const float4*)(aptr[i]); br[i] = *(const float4*)(bptr[i]); }

  for (int it = 0; it < 16; ++it) {
    __syncthreads();
#pragma unroll
    for (int i = 0; i < 4; ++i) { split3_write(lds, ar[i], aw[i]); split3_write(lds, br[i], bw[i]); }
    __syncthreads();
    if (it < 15) {
      const int ko = (it + 1) * 32;
#pragma unroll
      for (int i = 0; i < 4; ++i) { ar[i] = *(const float4*)(aptr[i] + ko); br[i] = *(const float4*)(bptr[i] + ko); }
    }
    s16x8 bf[4][3];
#pragma unroll
    for (int nf = 0; nf < 4; ++nf)
#pragma unroll
      for (int c = 0; c < 3; ++c)
        bf[nf][c] = *(const s16x8*)(lds + brow + nf * 16 * FB_ROWB + c * FB_COMP);
#pragma unroll
    for (int mf = 0; mf < 4; ++mf) {
      s16x8 af[3];
#pragma unroll
      for (int c = 0; c < 3; ++c)
        af[c] = *(const s16x8*)(lds + arow + mf * 16 * FB_ROWB + c * FB_COMP);
#pragma unroll
      for (int nf = 0; nf < 4; ++nf) {
        f32x4 c0 = acc[mf][nf];
        c0 = __builtin_amdgcn_mfma_f32_16x16x32_bf16(af[2], bf[nf][0], c0, 0, 0, 0);
        c0 = __builtin_amdgcn_mfma_f32_16x16x32_bf16(af[0], bf[nf][2], c0, 0, 0, 0);
        c0 = __builtin_amdgcn_mfma_f32_16x16x32_bf16(af[1], bf[nf][1], c0, 0, 0, 0);
        c0 = __builtin_amdgcn_mfma_f32_16x16x32_bf16(af[1], bf[nf][0], c0, 0, 0, 0);
        c0 = __builtin_amdgcn_mfma_f32_16x16x32_bf16(af[0], bf[nf][1], c0, 0, 0, 0);
        c0 = __builtin_amdgcn_mfma_f32_16x16x32_bf16(af[0], bf[nf][0], c0, 0, 0, 0);
        acc[mf][nf] = c0;
      }
    }
  }
  const int G = lane >> 4, col = lane & 15;
  const int bl = bl0 + wm * 4 + G;
#pragma unroll
  for (int nf = 0; nf < 4; ++nf) {
    const int n = n0 + wn * 64 + nf * 16 + col;
    const float bb = bias[n];
    float v = 0.0f;
#pragma unroll
    for (int t = 0; t < T_STEPS; ++t) {
      const float h = ((const float*)&acc[t >> 2][nf])[t & 3] + bb;
      const float vn = v + (h - v) * 0.5f;
      const bool s = (vn >= 1.0f);
      out[(size_t)(t * BLTOT + bl) * NDIM + n] = s ? 1.0f : 0.0f;
      v = s ? 0.0f : vn;
    }
  }
}

extern "C" void kernel_launch(void* const* d_in, const int* in_sizes, int n_in,
                              void* d_out, int out_size, void* d_ws, size_t ws_size,
                              hipStream_t stream) {
  const float* x = (const float*)d_in[0];
  const float* W = (const float*)d_in[1];
  const float* b = (const float*)d_in[2];
  float* out = (float*)d_out;

  if (ws_size >= WS_NEED) {
    char* ws = (char*)d_ws;
    split_w<<<128, 256, 0, stream>>>(W, ws);
    split_x<<<16384, 256, 0, stream>>>(x, ws);
    gemm_lif_frag<<<2048, 256, 0, stream>>>(ws, ws + ABASE, b, out);
  } else {
    dim3 grid(BLTOT / 8, NDIM / 128);
    fused_mfma_lif_fb<<<grid, 256, 0, stream>>>(x, W, b, out);
  }
}